// Round 14
// baseline (1136.098 us; speedup 1.0000x reference)
//
#include <hip/hip_runtime.h>
#include <math.h>

#define N_NODES 50000
#define N_EDGES 500000
#define G_GRAPHS 100
#define NPG 500
#define NPROT 400
#define H 128
#define PN 35
#define LN 11
#define DIN 261      // 2H + 1 + 4
#define EB2 32       // edges per block (MFMA edge kernel)
#define FS2 136      // bf16 plane row stride (272B = 68 dw, %32=4 -> 2-way, free)
#define NBN 64       // nodes per block (p12 kernel)
#define NB2 32       // nodes per block (MFMA node kernel)
#define CST 264      // node cat plane stride in bf16 (2-way, free)
#define NB 16        // nodes per workgroup (proj kernel)
#define NCHUNK 49    // ceil(N_NODES / 1024) for the scan
#define EPSV 1e-5f

typedef __attribute__((ext_vector_type(8))) short bf8_t;   // 8 bf16 (4 VGPRs)
typedef __attribute__((ext_vector_type(4))) short bf4_t;
typedef __attribute__((ext_vector_type(4))) float f4_t;

// fast silu: v_exp + v_rcp (~1ulp) instead of IEEE div sequence
__device__ __forceinline__ float silu_f(float x) {
    return x * __builtin_amdgcn_rcpf(1.0f + __expf(-x));
}
// RNE bf16 (weight prep only)
__device__ __forceinline__ short f2b(float f) {
    __bf16 b = (__bf16)f;
    return __builtin_bit_cast(short, b);
}
__device__ __forceinline__ float b2f(short s) {
    unsigned u = ((unsigned)(unsigned short)s) << 16;
    return __builtin_bit_cast(float, u);
}
// fast round-half-up bf16 (2 int ops) - error <= 2^-9 rel, same bound as RNE
__device__ __forceinline__ short f2b_fast(float f) {
    unsigned b = __builtin_bit_cast(unsigned, f);
    return (short)((b + 0x8000u) >> 16);
}
// fast hi/lo split: hi rounded-half-up, lo = bf16(v - hi)
__device__ __forceinline__ short2 split_hl(float v) {
    unsigned b = __builtin_bit_cast(unsigned, v);
    unsigned hr = (b + 0x8000u) & 0xFFFF0000u;
    float lf = v - __builtin_bit_cast(float, hr);   // exact (hi within 2^-9 of v)
    unsigned lb = __builtin_bit_cast(unsigned, lf);
    short2 r;
    r.x = (short)(hr >> 16);
    r.y = (short)((lb + 0x8000u) >> 16);
    return r;
}

// ---- combined weight prep: all 6 weight groups in one launch ----
__global__ __launch_bounds__(256) void wprep_all_kernel(
    const float* __restrict__ ew1, const float* __restrict__ ew2,
    const float* __restrict__ cw1, const float* __restrict__ nw1,
    const float* __restrict__ nw2,
    short* __restrict__ W1aH, short* __restrict__ W1aL,
    short* __restrict__ W1bH, short* __restrict__ W1bL,
    short* __restrict__ W2h, short* __restrict__ W2l,
    short* __restrict__ W3h, short* __restrict__ W3l,
    short* __restrict__ N1h, short* __restrict__ N1l,
    short* __restrict__ N2h, short* __restrict__ N2l)
{
    int idx = blockIdx.x * 256 + threadIdx.x;
    const float* src; short *dh, *dl; int Ksrc, nkb, koff, base;
    if (idx < 65536)       { src = ew1; dh = W1aH; dl = W1aL; Ksrc = DIN; nkb = 4; koff = 0; base = 0; }
    else if (idx < 131072) { src = ew1; dh = W1bH; dl = W1bL; Ksrc = DIN; nkb = 4; koff = H; base = 65536; }
    else if (idx < 196608) { src = ew2; dh = W2h;  dl = W2l;  Ksrc = H;   nkb = 4; koff = 0; base = 131072; }
    else if (idx < 262144) { src = cw1; dh = W3h;  dl = W3l;  Ksrc = H;   nkb = 4; koff = 0; base = 196608; }
    else if (idx < 393216) { src = nw1; dh = N1h;  dl = N1l;  Ksrc = 256; nkb = 8; koff = 0; base = 262144; }
    else if (idx < 458752) { src = nw2; dh = N2h;  dl = N2l;  Ksrc = H;   nkb = 4; koff = 0; base = 393216; }
    else return;
    int rem0 = idx - base;
    int per_l = nkb * 8 * 64 * 8;
    int l = rem0 / per_l;
    int rem = rem0 - l * per_l;
    int j = rem & 7;
    int lane = (rem >> 3) & 63;
    int nt = (rem >> 9) & 7;
    int kb = rem >> 12;
    int ln = lane & 15, quad = lane >> 4;
    int n = nt * 16 + ln;
    int k = koff + kb * 32 + quad * 8 + j;
    float v = (k < Ksrc) ? src[((size_t)l * Ksrc + k) * H + n] : 0.0f;
    short hi = f2b(v);
    dh[rem0] = hi;
    dl[rem0] = f2b(v - b2f(hi));
}

// ---------------- edge sort: counting sort by target row ----------------
__global__ void hist_kernel(const int* __restrict__ ei, int* __restrict__ cnt)
{
    int e = blockIdx.x * 256 + threadIdx.x;
    if (e < N_EDGES) atomicAdd(&cnt[ei[e]], 1);
}

__global__ __launch_bounds__(256) void bsum_kernel(const int* __restrict__ cnt, int* __restrict__ bsum)
{
    __shared__ int red[4];
    int tid = threadIdx.x;
    int i0 = blockIdx.x * 1024 + tid * 4;
    int s = 0;
    #pragma unroll
    for (int j = 0; j < 4; j++) {
        int i = i0 + j;
        if (i < N_NODES) s += cnt[i];
    }
    #pragma unroll
    for (int off = 32; off > 0; off >>= 1) s += __shfl_down(s, off, 64);
    if ((tid & 63) == 0) red[tid >> 6] = s;
    __syncthreads();
    if (tid == 0) bsum[blockIdx.x] = red[0] + red[1] + red[2] + red[3];
}

__global__ void scanb_kernel(const int* __restrict__ bsum, int* __restrict__ boff)
{
    if (threadIdx.x == 0) {
        int acc = 0;
        for (int i = 0; i < NCHUNK; i++) { boff[i] = acc; acc += bsum[i]; }
    }
}

__global__ __launch_bounds__(256) void scanc_kernel(const int* __restrict__ cnt,
                                                    const int* __restrict__ boff,
                                                    int* __restrict__ base,
                                                    float* __restrict__ deg)
{
    __shared__ int ts[256];
    int tid = threadIdx.x;
    int b = blockIdx.x;
    int i0 = b * 1024 + tid * 4;
    int v0 = (i0 + 0 < N_NODES) ? cnt[i0 + 0] : 0;
    int v1 = (i0 + 1 < N_NODES) ? cnt[i0 + 1] : 0;
    int v2 = (i0 + 2 < N_NODES) ? cnt[i0 + 2] : 0;
    int v3 = (i0 + 3 < N_NODES) ? cnt[i0 + 3] : 0;
    int s0 = v0, s1 = s0 + v1, s2 = s1 + v2, s3 = s2 + v3;
    ts[tid] = s3;
    __syncthreads();
    for (int off = 1; off < 256; off <<= 1) {
        int t = (tid >= off) ? ts[tid - off] : 0;
        __syncthreads();
        ts[tid] += t;
        __syncthreads();
    }
    int excl = ((tid > 0) ? ts[tid - 1] : 0) + boff[b];
    if (i0 + 0 < N_NODES) { base[i0 + 0] = excl;      deg[i0 + 0] = (float)v0; }
    if (i0 + 1 < N_NODES) { base[i0 + 1] = excl + s0; deg[i0 + 1] = (float)v1; }
    if (i0 + 2 < N_NODES) { base[i0 + 2] = excl + s1; deg[i0 + 2] = (float)v2; }
    if (i0 + 3 < N_NODES) { base[i0 + 3] = excl + s2; deg[i0 + 3] = (float)v3; }
}

__global__ void scatter_kernel(const int* __restrict__ ei, const int* __restrict__ base,
                               int* __restrict__ cursor, int* __restrict__ perm,
                               int* __restrict__ rowsS)
{
    int e = blockIdx.x * 256 + threadIdx.x;
    if (e < N_EDGES) {
        int r = ei[e];
        int p = atomicAdd(&cursor[r], 1);
        int d = base[r] + p;
        perm[d] = e;
        rowsS[d] = r;
    }
}

// ---------------- projection ----------------
__global__ __launch_bounds__(128) void proj_kernel(
    const float* __restrict__ x, const float* __restrict__ Wp, const float* __restrict__ bp,
    const float* __restrict__ Wl, const float* __restrict__ bl, float* __restrict__ h)
{
    __shared__ float xs[NB][36];
    int tid = threadIdx.x;
    int n0 = blockIdx.x * NB;
    for (int idx = tid; idx < NB * PN; idx += 128) {
        int n = idx / PN, k = idx % PN;
        xs[n][k] = x[(size_t)(n0 + n) * PN + k];
    }
    __syncthreads();
    for (int n = 0; n < NB; n++) {
        int node = n0 + n;
        bool isp = (node % NPG) < NPROT;
        float acc;
        if (isp) {
            acc = bp[tid];
            for (int k = 0; k < PN; k++) acc = fmaf(xs[n][k], Wp[k * H + tid], acc);
        } else {
            acc = bl[tid];
            for (int k = 0; k < LN; k++) acc = fmaf(xs[n][k], Wl[k * H + tid], acc);
        }
        h[(size_t)node * H + tid] = acc;
    }
}

// ---------------- batchnorm stats ----------------
__global__ __launch_bounds__(128) void bn_stats_kernel(const float* __restrict__ h, float* __restrict__ bnS)
{
    int tid = threadIdx.x;
    size_t base = (size_t)blockIdx.x * NPG * H;
    float s1 = 0.f, s2 = 0.f;
    for (int i = 0; i < NPG; i++) {
        float v = h[base + (size_t)i * H + tid];
        s1 += v; s2 += v * v;
    }
    atomicAdd(&bnS[tid], s1);
    atomicAdd(&bnS[H + tid], s2);
}

__global__ void bn_final_kernel(const float* __restrict__ bnS, const float* __restrict__ gamma,
                                const float* __restrict__ beta, float* __restrict__ bnP)
{
    int j = threadIdx.x;
    float mu = bnS[j] / (float)N_NODES;
    float var = bnS[H + j] / (float)N_NODES - mu * mu;
    float inv = rsqrtf(var + EPSV);
    float sc = gamma[j] * inv;
    bnP[j] = sc;
    bnP[H + j] = beta[j] - mu * sc;
}

// ---- hi/lo bf16 MFMA k-loop: 2 m-tiles x 2 n-tiles per wave (3-term) ----
__device__ __forceinline__ void mm_hl2(
    const short* fH, const short* fL, int stride,
    const short* __restrict__ WH, const short* __restrict__ WL,
    int nkb, int nt0, int lane, int ln, int quad, f4_t acc[2][2])
{
    #pragma unroll
    for (int mi = 0; mi < 2; mi++)
        #pragma unroll
        for (int ni = 0; ni < 2; ni++) acc[mi][ni] = (f4_t)(0.0f);
    for (int kb = 0; kb < nkb; kb++) {
        int k0 = kb * 32 + quad * 8;
        bf8_t ah0 = *(const bf8_t*)&fH[(ln) * stride + k0];
        bf8_t al0 = *(const bf8_t*)&fL[(ln) * stride + k0];
        bf8_t ah1 = *(const bf8_t*)&fH[(16 + ln) * stride + k0];
        bf8_t al1 = *(const bf8_t*)&fL[(16 + ln) * stride + k0];
        #pragma unroll
        for (int ni = 0; ni < 2; ni++) {
            int off = ((kb * 8 + nt0 + ni) * 64 + lane) * 8;
            bf8_t bh = *(const bf8_t*)&WH[off];
            bf8_t bl = *(const bf8_t*)&WL[off];
            acc[0][ni] = __builtin_amdgcn_mfma_f32_16x16x32_bf16(ah0, bh, acc[0][ni], 0, 0, 0);
            acc[0][ni] = __builtin_amdgcn_mfma_f32_16x16x32_bf16(al0, bh, acc[0][ni], 0, 0, 0);
            acc[0][ni] = __builtin_amdgcn_mfma_f32_16x16x32_bf16(ah0, bl, acc[0][ni], 0, 0, 0);
            acc[1][ni] = __builtin_amdgcn_mfma_f32_16x16x32_bf16(ah1, bh, acc[1][ni], 0, 0, 0);
            acc[1][ni] = __builtin_amdgcn_mfma_f32_16x16x32_bf16(al1, bh, acc[1][ni], 0, 0, 0);
            acc[1][ni] = __builtin_amdgcn_mfma_f32_16x16x32_bf16(ah1, bl, acc[1][ni], 0, 0, 0);
        }
    }
}

// ---- 2-term variant: bf16 activations (hi only) x exact hi/lo weights ----
__device__ __forceinline__ void mm_h2t(
    const short* fH, int stride,
    const short* __restrict__ WH, const short* __restrict__ WL,
    int nkb, int nt0, int lane, int ln, int quad, f4_t acc[2][2])
{
    #pragma unroll
    for (int mi = 0; mi < 2; mi++)
        #pragma unroll
        for (int ni = 0; ni < 2; ni++) acc[mi][ni] = (f4_t)(0.0f);
    for (int kb = 0; kb < nkb; kb++) {
        int k0 = kb * 32 + quad * 8;
        bf8_t ah0 = *(const bf8_t*)&fH[(ln) * stride + k0];
        bf8_t ah1 = *(const bf8_t*)&fH[(16 + ln) * stride + k0];
        #pragma unroll
        for (int ni = 0; ni < 2; ni++) {
            int off = ((kb * 8 + nt0 + ni) * 64 + lane) * 8;
            bf8_t bh = *(const bf8_t*)&WH[off];
            bf8_t bl = *(const bf8_t*)&WL[off];
            acc[0][ni] = __builtin_amdgcn_mfma_f32_16x16x32_bf16(ah0, bh, acc[0][ni], 0, 0, 0);
            acc[0][ni] = __builtin_amdgcn_mfma_f32_16x16x32_bf16(ah0, bl, acc[0][ni], 0, 0, 0);
            acc[1][ni] = __builtin_amdgcn_mfma_f32_16x16x32_bf16(ah1, bh, acc[1][ni], 0, 0, 0);
            acc[1][ni] = __builtin_amdgcn_mfma_f32_16x16x32_bf16(ah1, bl, acc[1][ni], 0, 0, 0);
        }
    }
}

// ---------------- layer-0 pre-projection + fused BatchNorm apply ----------------
__global__ __launch_bounds__(512, 4) void p12_kernel(
    float* __restrict__ h, const float* __restrict__ bnP,
    const short* __restrict__ Ah, const short* __restrict__ Al,
    const short* __restrict__ Bh, const short* __restrict__ Bl,
    float* __restrict__ P1, float* __restrict__ P2)
{
    __shared__ __align__(16) short fH[NBN * FS2];
    __shared__ __align__(16) short fL[NBN * FS2];
    int tid = threadIdx.x;
    int n0 = blockIdx.x * NBN;

    for (int i = tid; i < NBN * (H / 4); i += 512) {
        int nidx = i >> 5, chunk = i & 31;
        int node0 = n0 + nidx;
        int node = (node0 < N_NODES) ? node0 : (N_NODES - 1);
        int ch4 = chunk * 4;
        f4_t v = *(const f4_t*)&h[(size_t)node * H + ch4];
        f4_t sc = *(const f4_t*)&bnP[ch4];
        f4_t sh = *(const f4_t*)&bnP[H + ch4];
        bf4_t hi, lo;
        #pragma unroll
        for (int j = 0; j < 4; j++) {
            float hn = fmaf(v[j], sc[j], sh[j]);
            v[j] = hn;
            short2 s = split_hl(hn);
            hi[j] = s.x; lo[j] = s.y;
        }
        if (node0 < N_NODES) *(f4_t*)&h[(size_t)node * H + ch4] = v;   // BN applied in place
        *(bf4_t*)&fH[nidx * FS2 + ch4] = hi;
        *(bf4_t*)&fL[nidx * FS2 + ch4] = lo;
    }
    __syncthreads();

    int lane = tid & 63;
    int nt = tid >> 6;
    int ln = lane & 15, quad = lane >> 4;

    f4_t accA[4], accB[4];
    #pragma unroll
    for (int mi = 0; mi < 4; mi++) { accA[mi] = (f4_t)(0.0f); accB[mi] = (f4_t)(0.0f); }
    for (int kb = 0; kb < 4; kb++) {
        int k0 = kb * 32 + quad * 8;
        int off = ((kb * 8 + nt) * 64 + lane) * 8;
        bf8_t bhA = *(const bf8_t*)&Ah[off];
        bf8_t blA = *(const bf8_t*)&Al[off];
        bf8_t bhB = *(const bf8_t*)&Bh[off];
        bf8_t blB = *(const bf8_t*)&Bl[off];
        #pragma unroll
        for (int mi = 0; mi < 4; mi++) {
            bf8_t ah = *(const bf8_t*)&fH[(mi * 16 + ln) * FS2 + k0];
            bf8_t al = *(const bf8_t*)&fL[(mi * 16 + ln) * FS2 + k0];
            accA[mi] = __builtin_amdgcn_mfma_f32_16x16x32_bf16(ah, bhA, accA[mi], 0, 0, 0);
            accA[mi] = __builtin_amdgcn_mfma_f32_16x16x32_bf16(al, bhA, accA[mi], 0, 0, 0);
            accA[mi] = __builtin_amdgcn_mfma_f32_16x16x32_bf16(ah, blA, accA[mi], 0, 0, 0);
            accB[mi] = __builtin_amdgcn_mfma_f32_16x16x32_bf16(ah, bhB, accB[mi], 0, 0, 0);
            accB[mi] = __builtin_amdgcn_mfma_f32_16x16x32_bf16(al, bhB, accB[mi], 0, 0, 0);
            accB[mi] = __builtin_amdgcn_mfma_f32_16x16x32_bf16(ah, blB, accB[mi], 0, 0, 0);
        }
    }
    int n = nt * 16 + ln;
    #pragma unroll
    for (int mi = 0; mi < 4; mi++) {
        #pragma unroll
        for (int r = 0; r < 4; r++) {
            int node = n0 + mi * 16 + quad * 4 + r;
            if (node < N_NODES) {
                P1[(size_t)node * H + n] = accA[mi][r];
                P2[(size_t)node * H + n] = accB[mi][r];
            }
        }
    }
}

// ---------------- MFMA edge kernel (EB=32, 256 thr, 8 blocks/CU, XCD-swizzled) ----------------
__global__ __launch_bounds__(256, 8) void edge_mfma_kernel(
    const float* __restrict__ P1, const float* __restrict__ P2,
    const float* __restrict__ pos,
    const int* __restrict__ ei, const float* __restrict__ eattr,
    const int* __restrict__ perm, const int* __restrict__ rowsS,
    const float* __restrict__ W1c, const float* __restrict__ eb1,
    const short* __restrict__ W2h, const short* __restrict__ W2l,
    const short* __restrict__ W3h, const short* __restrict__ W3l,
    const float* __restrict__ eb2,
    const float* __restrict__ cb1, const float* __restrict__ cw2,
    float* __restrict__ magg, float* __restrict__ pagg)
{
    __shared__ __align__(16) short fHL[2 * EB2 * FS2];   // 17408 B
    __shared__ float relS[EB2][3];
    __shared__ float attrS[EB2][5];
    __shared__ float wpart[EB2][4];
    __shared__ int rowS[EB2];
    __shared__ int rowG[EB2];
    __shared__ int colS[EB2];

    short* fH = fHL;
    short* fL = fHL + EB2 * FS2;
    int tid = threadIdx.x;
    int chunk = gridDim.x >> 3;
    int bx = blockIdx.x;
    int bid = (bx & 7) * chunk + (bx >> 3);
    int e0 = bid * EB2;

    // --- edge meta ---
    if (tid < EB2) {
        int e = e0 + tid;
        int eidx = (e < N_EDGES) ? e : (N_EDGES - 1);
        int ec = perm[eidx];
        int r = rowsS[eidx];
        int c = ei[N_EDGES + ec];
        rowG[tid] = r;
        rowS[tid] = (e < N_EDGES) ? r : -1;
        colS[tid] = c;
        float rx = pos[r * 3 + 0] - pos[c * 3 + 0];
        float ry = pos[r * 3 + 1] - pos[c * 3 + 1];
        float rz = pos[r * 3 + 2] - pos[c * 3 + 2];
        relS[tid][0] = rx; relS[tid][1] = ry; relS[tid][2] = rz;
        attrS[tid][0] = rx * rx + ry * ry + rz * rz;
        attrS[tid][1] = eattr[(size_t)ec * 4 + 0];
        attrS[tid][2] = eattr[(size_t)ec * 4 + 1];
        attrS[tid][3] = eattr[(size_t)ec * 4 + 2];
        attrS[tid][4] = eattr[(size_t)ec * 4 + 3];
    }
    __syncthreads();

    // --- fused stage 1, pair-batched for load ILP ---
    {
        int ch4 = (tid & 31) * 4;
        f4_t bb = *(const f4_t*)&eb1[ch4];
        f4_t w0 = *(const f4_t*)&W1c[0 * H + ch4];
        f4_t w1 = *(const f4_t*)&W1c[1 * H + ch4];
        f4_t w2 = *(const f4_t*)&W1c[2 * H + ch4];
        f4_t w3 = *(const f4_t*)&W1c[3 * H + ch4];
        f4_t w4 = *(const f4_t*)&W1c[4 * H + ch4];
        #pragma unroll
        for (int b = 0; b < 2; b++) {
            int i0 = tid + b * 512;
            int i1 = i0 + 256;
            int ea = i0 >> 5;
            int eb_ = i1 >> 5;
            f4_t p1a = *(const f4_t*)&P1[(size_t)rowG[ea] * H + ch4];
            f4_t p2a = __builtin_nontemporal_load((const f4_t*)&P2[(size_t)colS[ea] * H + ch4]);
            f4_t p1b = *(const f4_t*)&P1[(size_t)rowG[eb_] * H + ch4];
            f4_t p2b = __builtin_nontemporal_load((const f4_t*)&P2[(size_t)colS[eb_] * H + ch4]);
            #pragma unroll
            for (int half = 0; half < 2; half++) {
                int e = half ? eb_ : ea;
                f4_t p1 = half ? p1b : p1a;
                f4_t p2 = half ? p2b : p2a;
                float a0 = attrS[e][0], a1 = attrS[e][1], a2 = attrS[e][2];
                float a3 = attrS[e][3], a4 = attrS[e][4];
                bf4_t hi, lo;
                #pragma unroll
                for (int j = 0; j < 4; j++) {
                    float t = p1[j] + p2[j] + bb[j];
                    t = fmaf(a0, w0[j], t);
                    t = fmaf(a1, w1[j], t);
                    t = fmaf(a2, w2[j], t);
                    t = fmaf(a3, w3[j], t);
                    t = fmaf(a4, w4[j], t);
                    float v = silu_f(t);
                    short2 s = split_hl(v);
                    hi[j] = s.x; lo[j] = s.y;
                }
                *(bf4_t*)&fH[e * FS2 + ch4] = hi;
                *(bf4_t*)&fL[e * FS2 + ch4] = lo;
            }
        }
    }
    __syncthreads();

    int lane = tid & 63;
    int wv = tid >> 6;            // 4 waves
    int ln = lane & 15, quad = lane >> 4;
    int nt0 = wv * 2;             // each wave: 2 n-tiles

    f4_t acc[2][2];
    float t2s[2][2][4];

    // ===== stage 2: t2 = silu(t1 @ W2 + b2), K=128 (3-term) =====
    mm_hl2(fH, fL, FS2, W2h, W2l, 4, nt0, lane, ln, quad, acc);
    #pragma unroll
    for (int ni = 0; ni < 2; ni++) {
        int n = (nt0 + ni) * 16 + ln;
        float bb = eb2[n];
        #pragma unroll
        for (int mi = 0; mi < 2; mi++)
            #pragma unroll
            for (int r = 0; r < 4; r++)
                t2s[mi][ni][r] = silu_f(acc[mi][ni][r] + bb);
    }
    __syncthreads();   // all stage-2 reads of t1 done
    // t2 stored hi-only (bf16): feeds stage 3 AND the magg segmented reduce
    #pragma unroll
    for (int ni = 0; ni < 2; ni++) {
        int n = (nt0 + ni) * 16 + ln;
        #pragma unroll
        for (int mi = 0; mi < 2; mi++) {
            #pragma unroll
            for (int r = 0; r < 4; r++) {
                int m = mi * 16 + quad * 4 + r;
                fH[m * FS2 + n] = f2b_fast(t2s[mi][ni][r]);
            }
        }
    }
    __syncthreads();

    // ===== stage 3: w = silu(t2 @ Wc1 + cb1) @ cw2, K=128 (2-term) =====
    mm_h2t(fH, FS2, W3h, W3l, 4, nt0, lane, ln, quad, acc);
    {
        #pragma unroll
        for (int mi = 0; mi < 2; mi++) {
            #pragma unroll
            for (int r = 0; r < 4; r++) {
                float v = 0.f;
                #pragma unroll
                for (int ni = 0; ni < 2; ni++) {
                    int n = (nt0 + ni) * 16 + ln;
                    v += silu_f(acc[mi][ni][r] + cb1[n]) * cw2[n];
                }
                v += __shfl_xor(v, 1, 64);
                v += __shfl_xor(v, 2, 64);
                v += __shfl_xor(v, 4, 64);
                v += __shfl_xor(v, 8, 64);
                if (ln == 0) wpart[mi * 16 + quad * 4 + r][wv] = v;
            }
        }
    }
    __syncthreads();   // wpart written; t2-hi still valid in fH

    // --- segmented reduction over sorted rows (t2 read back from bf16 hi-plane) ---
    {
        int ch = tid & 127, seg = tid >> 7;
        int ebeg = seg * 16, eend = ebeg + 16;
        float a2 = 0.f; int cur = -1;
        for (int e2 = ebeg; e2 < eend; e2++) {
            int r2 = rowS[e2];
            float v2 = b2f(fH[e2 * FS2 + ch]);
            if (r2 != cur) {
                if (cur >= 0) atomicAdd(&magg[(size_t)cur * H + ch], a2);
                cur = r2; a2 = v2;
            } else a2 += v2;
        }
        if (cur >= 0) atomicAdd(&magg[(size_t)cur * H + ch], a2);
    }
    if (tid < 6) {
        int ax = tid % 3, seg = tid / 3;
        int ebeg = seg * 16, eend = ebeg + 16;
        float a2 = 0.f; int cur = -1;
        for (int e2 = ebeg; e2 < eend; e2++) {
            int r2 = rowS[e2];
            float w2 = (wpart[e2][0] + wpart[e2][1] + wpart[e2][2] + wpart[e2][3]) * relS[e2][ax];
            if (r2 != cur) {
                if (cur >= 0) atomicAdd(&pagg[(size_t)cur * 3 + ax], a2);
                cur = r2; a2 = w2;
            } else a2 += w2;
        }
        if (cur >= 0) atomicAdd(&pagg[(size_t)cur * 3 + ax], a2);
    }
}

// ---------------- MFMA node kernel (NB2=32, 256 thr) + fused next-layer P1/P2 ----------------
__global__ __launch_bounds__(256, 8) void node_mfma_kernel(
    float* __restrict__ h, float* __restrict__ magg,
    float* __restrict__ pagg, const float* __restrict__ deg,
    float* __restrict__ pos,
    const short* __restrict__ N1h, const short* __restrict__ N1l,
    const short* __restrict__ N2h, const short* __restrict__ N2l,
    const float* __restrict__ nb1, const float* __restrict__ nb2,
    const short* __restrict__ Ah, const short* __restrict__ Al,
    const short* __restrict__ Bh, const short* __restrict__ Bl,
    float* __restrict__ P1, float* __restrict__ P2, int doP)
{
    __shared__ __align__(16) short fH[NB2 * CST];   // 16896 B
    __shared__ __align__(16) short fL[NB2 * CST];   // 16896 B

    int tid = threadIdx.x;
    int n0 = blockIdx.x * NB2;

    if (tid < NB2 * 3) {
        int n = tid / 3, ax = tid - n * 3;
        int node = n0 + n;
        if (node < N_NODES) {
            float d = fmaxf(deg[node], 1.0f);
            pos[node * 3 + ax] += pagg[node * 3 + ax] / d;
            if (doP) pagg[node * 3 + ax] = 0.0f;
        }
    }

    for (int i = tid; i < 2 * NB2 * (H / 4); i += 256) {
        int rrow = i >> 5, chunk = i & 31;
        int nidx = rrow & (NB2 - 1);
        int node0 = n0 + nidx;
        int node = (node0 < N_NODES) ? node0 : (N_NODES - 1);
        const float* src = (rrow < NB2) ? h : magg;
        f4_t v = *(const f4_t*)&src[(size_t)node * H + chunk * 4];
        if (rrow >= NB2 && doP && node0 < N_NODES)
            *(f4_t*)&magg[(size_t)node * H + chunk * 4] = (f4_t)(0.0f);
        bf4_t hi, lo;
        #pragma unroll
        for (int j = 0; j < 4; j++) {
            short2 s = split_hl(v[j]);
            hi[j] = s.x; lo[j] = s.y;
        }
        int dcol = ((rrow < NB2) ? 0 : H) + chunk * 4;
        *(bf4_t*)&fH[nidx * CST + dcol] = hi;
        *(bf4_t*)&fL[nidx * CST + dcol] = lo;
    }
    __syncthreads();

    int lane = tid & 63;
    int wv = tid >> 6;
    int ln = lane & 15, quad = lane >> 4;
    int nt0 = wv * 2;

    f4_t acc[2][2];
    float u1s[2][2][4];

    // stage A: u1 = silu(cat @ N1 + nb1), K=256
    mm_hl2(fH, fL, CST, N1h, N1l, 8, nt0, lane, ln, quad, acc);
    #pragma unroll
    for (int ni = 0; ni < 2; ni++) {
        int n = (nt0 + ni) * 16 + ln;
        float bb = nb1[n];
        #pragma unroll
        for (int mi = 0; mi < 2; mi++)
            #pragma unroll
            for (int r = 0; r < 4; r++)
                u1s[mi][ni][r] = silu_f(acc[mi][ni][r] + bb);
    }
    __syncthreads();
    #pragma unroll
    for (int ni = 0; ni < 2; ni++) {
        int n = (nt0 + ni) * 16 + ln;
        #pragma unroll
        for (int mi = 0; mi < 2; mi++) {
            #pragma unroll
            for (int r = 0; r < 4; r++) {
                int m = mi * 16 + quad * 4 + r;
                short2 s = split_hl(u1s[mi][ni][r]);
                fH[m * CST + n] = s.x;
                fL[m * CST + n] = s.y;
            }
        }
    }
    __syncthreads();

    // stage B: h_new = h + u1 @ N2 + nb2; write h, stage h_new hi/lo for P GEMMs
    mm_hl2(fH, fL, CST, N2h, N2l, 4, nt0, lane, ln, quad, acc);
    __syncthreads();
    #pragma unroll
    for (int ni = 0; ni < 2; ni++) {
        int n = (nt0 + ni) * 16 + ln;
        float bb = nb2[n];
        #pragma unroll
        for (int mi = 0; mi < 2; mi++) {
            #pragma unroll
            for (int r = 0; r < 4; r++) {
                int m = mi * 16 + quad * 4 + r;
                int node = n0 + m;
                int nc = (node < N_NODES) ? node : (N_NODES - 1);
                float hn = h[(size_t)nc * H + n] + acc[mi][ni][r] + bb;
                if (node < N_NODES) h[(size_t)node * H + n] = hn;
                short2 s = split_hl(hn);
                fH[m * CST + n] = s.x;
                fL[m * CST + n] = s.y;
            }
        }
    }
    if (!doP) return;
    __syncthreads();

    // fused P GEMMs for next layer: P1 = h_new@W1a, P2 = h_new@W1b (K=128)
    f4_t accA[2][2], accB[2][2];
    #pragma unroll
    for (int mi = 0; mi < 2; mi++)
        #pragma unroll
        for (int ni = 0; ni < 2; ni++) { accA[mi][ni] = (f4_t)(0.0f); accB[mi][ni] = (f4_t)(0.0f); }
    for (int kb = 0; kb < 4; kb++) {
        int k0 = kb * 32 + quad * 8;
        bf8_t ah0 = *(const bf8_t*)&fH[(ln) * CST + k0];
        bf8_t al0 = *(const bf8_t*)&fL[(ln) * CST + k0];
        bf8_t ah1 = *(const bf8_t*)&fH[(16 + ln) * CST + k0];
        bf8_t al1 = *(const bf8_t*)&fL[(16 + ln) * CST + k0];
        #pragma unroll
        for (int ni = 0; ni < 2; ni++) {
            int off = ((kb * 8 + nt0 + ni) * 64 + lane) * 8;
            bf8_t bhA = *(const bf8_t*)&Ah[off];
            bf8_t blA = *(const bf8_t*)&Al[off];
            bf8_t bhB = *(const bf8_t*)&Bh[off];
            bf8_t blB = *(const bf8_t*)&Bl[off];
            accA[0][ni] = __builtin_amdgcn_mfma_f32_16x16x32_bf16(ah0, bhA, accA[0][ni], 0, 0, 0);
            accA[0][ni] = __builtin_amdgcn_mfma_f32_16x16x32_bf16(al0, bhA, accA[0][ni], 0, 0, 0);
            accA[0][ni] = __builtin_amdgcn_mfma_f32_16x16x32_bf16(ah0, blA, accA[0][ni], 0, 0, 0);
            accA[1][ni] = __builtin_amdgcn_mfma_f32_16x16x32_bf16(ah1, bhA, accA[1][ni], 0, 0, 0);
            accA[1][ni] = __builtin_amdgcn_mfma_f32_16x16x32_bf16(al1, bhA, accA[1][ni], 0, 0, 0);
            accA[1][ni] = __builtin_amdgcn_mfma_f32_16x16x32_bf16(ah1, blA, accA[1][ni], 0, 0, 0);
            accB[0][ni] = __builtin_amdgcn_mfma_f32_16x16x32_bf16(ah0, bhB, accB[0][ni], 0, 0, 0);
            accB[0][ni] = __builtin_amdgcn_mfma_f32_16x16x32_bf16(al0, bhB, accB[0][ni], 0, 0, 0);
            accB[0][ni] = __builtin_amdgcn_mfma_f32_16x16x32_bf16(ah0, blB, accB[0][ni], 0, 0, 0);
            accB[1][ni] = __builtin_amdgcn_mfma_f32_16x16x32_bf16(ah1, bhB, accB[1][ni], 0, 0, 0);
            accB[1][ni] = __builtin_amdgcn_mfma_f32_16x16x32_bf16(al1, bhB, accB[1][ni], 0, 0, 0);
            accB[1][ni] = __builtin_amdgcn_mfma_f32_16x16x32_bf16(ah1, blB, accB[1][ni], 0, 0, 0);
        }
    }
    #pragma unroll
    for (int ni = 0; ni < 2; ni++) {
        int n = (nt0 + ni) * 16 + ln;
        #pragma unroll
        for (int mi = 0; mi < 2; mi++) {
            #pragma unroll
            for (int r = 0; r < 4; r++) {
                int node = n0 + mi * 16 + quad * 4 + r;
                if (node < N_NODES) {
                    P1[(size_t)node * H + n] = accA[mi][ni][r];
                    P2[(size_t)node * H + n] = accB[mi][ni][r];
                }
            }
        }
    }
}

// ---------------- pooling + head ----------------
__global__ __launch_bounds__(128) void head_kernel(
    const float* __restrict__ h,
    const float* __restrict__ h1w, const float* __restrict__ h1b,
    const float* __restrict__ h2w, const float* __restrict__ h2b,
    const float* __restrict__ h3w, const float* __restrict__ h3b,
    float* __restrict__ out)
{
    __shared__ float gfeat[256];
    __shared__ float z1[128];
    __shared__ float z2[64];
    int tid = threadIdx.x;
    int g = blockIdx.x;
    size_t base = (size_t)g * NPG * H;
    float s = 0.f;
    for (int i = 0; i < NPG; i++) s += h[base + (size_t)i * H + tid];
    gfeat[tid] = s;
    gfeat[H + tid] = s / (float)NPG;
    __syncthreads();
    float a = h1b[tid];
    for (int k = 0; k < 256; k++) a = fmaf(gfeat[k], h1w[k * H + tid], a);
    z1[tid] = fmaxf(a, 0.0f);
    __syncthreads();
    if (tid < 64) {
        float a2 = h2b[tid];
        for (int k = 0; k < 128; k++) a2 = fmaf(z1[k], h2w[k * 64 + tid], a2);
        z2[tid] = fmaxf(a2, 0.0f);
    }
    __syncthreads();
    if (tid < 64) {
        float v = z2[tid] * h3w[tid];
        #pragma unroll
        for (int off = 32; off > 0; off >>= 1) v += __shfl_xor(v, off, 64);
        if (tid == 0) out[g] = v + h3b[0];
    }
}

extern "C" void kernel_launch(void* const* d_in, const int* in_sizes, int n_in,
                              void* d_out, int out_size, void* d_ws, size_t ws_size,
                              hipStream_t stream) {
    const float* x      = (const float*)d_in[0];
    const float* pos_in = (const float*)d_in[1];
    const int*   ei     = (const int*)d_in[2];
    const float* eattr  = (const float*)d_in[3];
    const float* Wp    = (const float*)d_in[6];
    const float* bp    = (const float*)d_in[7];
    const float* Wl    = (const float*)d_in[8];
    const float* bl    = (const float*)d_in[9];
    const float* gamma = (const float*)d_in[10];
    const float* beta  = (const float*)d_in[11];
    const float* ew1   = (const float*)d_in[12];
    const float* eb1   = (const float*)d_in[13];
    const float* ew2   = (const float*)d_in[14];
    const float* eb2   = (const float*)d_in[15];
    const float* cw1   = (const float*)d_in[16];
    const float* cb1   = (const float*)d_in[17];
    const float* cw2   = (const float*)d_in[18];
    const float* nw1   = (const float*)d_in[19];
    const float* nb1   = (const float*)d_in[20];
    const float* nw2   = (const float*)d_in[21];
    const float* nb2   = (const float*)d_in[22];
    const float* h1w   = (const float*)d_in[23];
    const float* h1b   = (const float*)d_in[24];
    const float* h2w   = (const float*)d_in[25];
    const float* h2b   = (const float*)d_in[26];
    const float* h3w   = (const float*)d_in[27];
    const float* h3b   = (const float*)d_in[28];
    float* out = (float*)d_out;

    float* ws   = (float*)d_ws;
    float* hbuf = ws;                                  // N*H f32
    float* magg = hbuf + (size_t)N_NODES * H;          // N*H f32
    float* P1   = magg + (size_t)N_NODES * H;          // N*H f32
    float* P2   = P1 + (size_t)N_NODES * H;            // N*H f32
    float* posb = P2 + (size_t)N_NODES * H;            // N*3
    float* pagg = posb + (size_t)N_NODES * 3;          // N*3
    float* deg  = pagg + (size_t)N_NODES * 3;          // N
    float* bnS  = deg + N_NODES;                       // 256
    float* bnP  = bnS + 256;                           // 256
    int* cnt    = (int*)(bnP + 256);                   // N
    int* basep  = cnt + N_NODES;                       // N
    int* cursor = basep + N_NODES;                     // N
    int* perm   = cursor + N_NODES;                    // E
    int* rowsS  = perm + N_EDGES;                      // E
    int* bsum   = rowsS + N_EDGES;                     // 64
    int* boff   = bsum + 64;                           // 64
    int szK4 = 4 * 4 * 4096;
    int szK8 = 4 * 8 * 4096;
    short* W1aH = (short*)(boff + 64);
    short* W1aL = W1aH + szK4;
    short* W1bH = W1aL + szK4;
    short* W1bL = W1bH + szK4;
    short* W2h  = W1bL + szK4;
    short* W2l  = W2h + szK4;
    short* W3h  = W2l + szK4;
    short* W3l  = W3h + szK4;
    short* N1h  = W3l + szK4;
    short* N1l  = N1h + szK8;
    short* N2h  = N1l + szK8;
    short* N2l  = N2h + szK4;

    (void)hipMemcpyAsync(posb, pos_in, (size_t)N_NODES * 3 * sizeof(float),
                         hipMemcpyDeviceToDevice, stream);
    (void)hipMemsetAsync(cnt, 0, N_NODES * sizeof(int), stream);
    (void)hipMemsetAsync(cursor, 0, N_NODES * sizeof(int), stream);
    (void)hipMemsetAsync(bnS, 0, 256 * sizeof(float), stream);
    (void)hipMemsetAsync(magg, 0, (size_t)N_NODES * H * sizeof(float), stream);
    (void)hipMemsetAsync(pagg, 0, (size_t)N_NODES * 3 * sizeof(float), stream);

    hist_kernel<<<(N_EDGES + 255) / 256, 256, 0, stream>>>(ei, cnt);
    bsum_kernel<<<NCHUNK, 256, 0, stream>>>(cnt, bsum);
    scanb_kernel<<<1, 64, 0, stream>>>(bsum, boff);
    scanc_kernel<<<NCHUNK, 256, 0, stream>>>(cnt, boff, basep, deg);
    scatter_kernel<<<(N_EDGES + 255) / 256, 256, 0, stream>>>(ei, basep, cursor, perm, rowsS);

    wprep_all_kernel<<<458752 / 256, 256, 0, stream>>>(
        ew1, ew2, cw1, nw1, nw2,
        W1aH, W1aL, W1bH, W1bL, W2h, W2l, W3h, W3l, N1h, N1l, N2h, N2l);

    proj_kernel<<<N_NODES / NB, 128, 0, stream>>>(x, Wp, bp, Wl, bl, hbuf);
    bn_stats_kernel<<<N_NODES / NPG, 128, 0, stream>>>(hbuf, bnS);
    bn_final_kernel<<<1, 128, 0, stream>>>(bnS, gamma, beta, bnP);

    int eblocks = (N_EDGES + EB2 - 1) / EB2;
    int echunk = (eblocks + 7) / 8;
    int eblocks_pad = echunk * 8;
    int nblocks = (N_NODES + NBN - 1) / NBN;     // p12 (64-node)
    int nblocks2 = (N_NODES + NB2 - 1) / NB2;    // node kernel (32-node)

    // layer-0 P1/P2 with fused BatchNorm apply (h updated in place)
    p12_kernel<<<nblocks, 512, 0, stream>>>(hbuf, bnP, W1aH, W1aL, W1bH, W1bL, P1, P2);

    for (int l = 0; l < 4; l++) {
        edge_mfma_kernel<<<eblocks_pad, 256, 0, stream>>>(
            P1, P2, posb, ei, eattr, perm, rowsS,
            ew1 + (size_t)l * DIN * H + (size_t)2 * H * H,   // W1c rows 256..260
            eb1 + (size_t)l * H,
            W2h + (size_t)l * 4 * 4096, W2l + (size_t)l * 4 * 4096,
            W3h + (size_t)l * 4 * 4096, W3l + (size_t)l * 4 * 4096,
            eb2 + (size_t)l * H,
            cb1 + (size_t)l * H, cw2 + (size_t)l * H,
            magg, pagg);
        int lp = l + 1;
        node_mfma_kernel<<<nblocks2, 256, 0, stream>>>(
            hbuf, magg, pagg, deg, posb,
            N1h + (size_t)l * 8 * 4096, N1l + (size_t)l * 8 * 4096,
            N2h + (size_t)l * 4 * 4096, N2l + (size_t)l * 4 * 4096,
            nb1 + (size_t)l * H, nb2 + (size_t)l * H,
            W1aH + (size_t)(lp & 3) * 4 * 4096, W1aL + (size_t)(lp & 3) * 4 * 4096,
            W1bH + (size_t)(lp & 3) * 4 * 4096, W1bL + (size_t)(lp & 3) * 4 * 4096,
            P1, P2, (l < 3) ? 1 : 0);
    }

    head_kernel<<<G_GRAPHS, 128, 0, stream>>>(hbuf, h1w, h1b, h2w, h2b, h3w, h3b, out);
}

// Round 15
// 1057.251 us; speedup vs baseline: 1.0746x; 1.0746x over previous
//
#include <hip/hip_runtime.h>
#include <math.h>

#define N_NODES 50000
#define N_EDGES 500000
#define G_GRAPHS 100
#define NPG 500
#define NPROT 400
#define H 128
#define PN 35
#define LN 11
#define DIN 261      // 2H + 1 + 4
#define EB2 32       // edges per block (MFMA edge kernel)
#define FS2 136      // bf16 plane row stride (272B = 68 dw, %32=4 -> 2-way, free)
#define NBN 64       // nodes per block (p12 kernel)
#define NB2 32       // nodes per block (MFMA node kernel)
#define CST 264      // node cat plane stride in bf16 (2-way, free)
#define NB 16        // nodes per workgroup (proj kernel)
#define NCHUNK 49    // ceil(N_NODES / 1024) for the scan
#define EPSV 1e-5f

typedef __attribute__((ext_vector_type(8))) short bf8_t;   // 8 bf16 (4 VGPRs)
typedef __attribute__((ext_vector_type(4))) short bf4_t;
typedef __attribute__((ext_vector_type(4))) float f4_t;

// fast silu: v_exp + v_rcp (~1ulp) instead of IEEE div sequence
__device__ __forceinline__ float silu_f(float x) {
    return x * __builtin_amdgcn_rcpf(1.0f + __expf(-x));
}
// RNE bf16 (weight prep only)
__device__ __forceinline__ short f2b(float f) {
    __bf16 b = (__bf16)f;
    return __builtin_bit_cast(short, b);
}
__device__ __forceinline__ float b2f(short s) {
    unsigned u = ((unsigned)(unsigned short)s) << 16;
    return __builtin_bit_cast(float, u);
}
// fast round-half-up bf16 (2 int ops) - error <= 2^-9 rel, same bound as RNE
__device__ __forceinline__ short f2b_fast(float f) {
    unsigned b = __builtin_bit_cast(unsigned, f);
    return (short)((b + 0x8000u) >> 16);
}
// fast hi/lo split: hi rounded-half-up, lo = bf16(v - hi)
__device__ __forceinline__ short2 split_hl(float v) {
    unsigned b = __builtin_bit_cast(unsigned, v);
    unsigned hr = (b + 0x8000u) & 0xFFFF0000u;
    float lf = v - __builtin_bit_cast(float, hr);   // exact (hi within 2^-9 of v)
    unsigned lb = __builtin_bit_cast(unsigned, lf);
    short2 r;
    r.x = (short)(hr >> 16);
    r.y = (short)((lb + 0x8000u) >> 16);
    return r;
}

// ---- combined weight prep: all 6 weight groups in one launch ----
__global__ __launch_bounds__(256) void wprep_all_kernel(
    const float* __restrict__ ew1, const float* __restrict__ ew2,
    const float* __restrict__ cw1, const float* __restrict__ nw1,
    const float* __restrict__ nw2,
    short* __restrict__ W1aH, short* __restrict__ W1aL,
    short* __restrict__ W1bH, short* __restrict__ W1bL,
    short* __restrict__ W2h, short* __restrict__ W2l,
    short* __restrict__ W3h, short* __restrict__ W3l,
    short* __restrict__ N1h, short* __restrict__ N1l,
    short* __restrict__ N2h, short* __restrict__ N2l)
{
    int idx = blockIdx.x * 256 + threadIdx.x;
    const float* src; short *dh, *dl; int Ksrc, nkb, koff, base;
    if (idx < 65536)       { src = ew1; dh = W1aH; dl = W1aL; Ksrc = DIN; nkb = 4; koff = 0; base = 0; }
    else if (idx < 131072) { src = ew1; dh = W1bH; dl = W1bL; Ksrc = DIN; nkb = 4; koff = H; base = 65536; }
    else if (idx < 196608) { src = ew2; dh = W2h;  dl = W2l;  Ksrc = H;   nkb = 4; koff = 0; base = 131072; }
    else if (idx < 262144) { src = cw1; dh = W3h;  dl = W3l;  Ksrc = H;   nkb = 4; koff = 0; base = 196608; }
    else if (idx < 393216) { src = nw1; dh = N1h;  dl = N1l;  Ksrc = 256; nkb = 8; koff = 0; base = 262144; }
    else if (idx < 458752) { src = nw2; dh = N2h;  dl = N2l;  Ksrc = H;   nkb = 4; koff = 0; base = 393216; }
    else return;
    int rem0 = idx - base;
    int per_l = nkb * 8 * 64 * 8;
    int l = rem0 / per_l;
    int rem = rem0 - l * per_l;
    int j = rem & 7;
    int lane = (rem >> 3) & 63;
    int nt = (rem >> 9) & 7;
    int kb = rem >> 12;
    int ln = lane & 15, quad = lane >> 4;
    int n = nt * 16 + ln;
    int k = koff + kb * 32 + quad * 8 + j;
    float v = (k < Ksrc) ? src[((size_t)l * Ksrc + k) * H + n] : 0.0f;
    short hi = f2b(v);
    dh[rem0] = hi;
    dl[rem0] = f2b(v - b2f(hi));
}

// ---------------- edge sort: counting sort by target row ----------------
__global__ void hist_kernel(const int* __restrict__ ei, int* __restrict__ cnt)
{
    int e = blockIdx.x * 256 + threadIdx.x;
    if (e < N_EDGES) atomicAdd(&cnt[ei[e]], 1);
}

__global__ __launch_bounds__(256) void bsum_kernel(const int* __restrict__ cnt, int* __restrict__ bsum)
{
    __shared__ int red[4];
    int tid = threadIdx.x;
    int i0 = blockIdx.x * 1024 + tid * 4;
    int s = 0;
    #pragma unroll
    for (int j = 0; j < 4; j++) {
        int i = i0 + j;
        if (i < N_NODES) s += cnt[i];
    }
    #pragma unroll
    for (int off = 32; off > 0; off >>= 1) s += __shfl_down(s, off, 64);
    if ((tid & 63) == 0) red[tid >> 6] = s;
    __syncthreads();
    if (tid == 0) bsum[blockIdx.x] = red[0] + red[1] + red[2] + red[3];
}

__global__ void scanb_kernel(const int* __restrict__ bsum, int* __restrict__ boff)
{
    if (threadIdx.x == 0) {
        int acc = 0;
        for (int i = 0; i < NCHUNK; i++) { boff[i] = acc; acc += bsum[i]; }
    }
}

__global__ __launch_bounds__(256) void scanc_kernel(const int* __restrict__ cnt,
                                                    const int* __restrict__ boff,
                                                    int* __restrict__ base,
                                                    float* __restrict__ deg)
{
    __shared__ int ts[256];
    int tid = threadIdx.x;
    int b = blockIdx.x;
    int i0 = b * 1024 + tid * 4;
    int v0 = (i0 + 0 < N_NODES) ? cnt[i0 + 0] : 0;
    int v1 = (i0 + 1 < N_NODES) ? cnt[i0 + 1] : 0;
    int v2 = (i0 + 2 < N_NODES) ? cnt[i0 + 2] : 0;
    int v3 = (i0 + 3 < N_NODES) ? cnt[i0 + 3] : 0;
    int s0 = v0, s1 = s0 + v1, s2 = s1 + v2, s3 = s2 + v3;
    ts[tid] = s3;
    __syncthreads();
    for (int off = 1; off < 256; off <<= 1) {
        int t = (tid >= off) ? ts[tid - off] : 0;
        __syncthreads();
        ts[tid] += t;
        __syncthreads();
    }
    int excl = ((tid > 0) ? ts[tid - 1] : 0) + boff[b];
    if (i0 + 0 < N_NODES) { base[i0 + 0] = excl;      deg[i0 + 0] = (float)v0; }
    if (i0 + 1 < N_NODES) { base[i0 + 1] = excl + s0; deg[i0 + 1] = (float)v1; }
    if (i0 + 2 < N_NODES) { base[i0 + 2] = excl + s1; deg[i0 + 2] = (float)v2; }
    if (i0 + 3 < N_NODES) { base[i0 + 3] = excl + s2; deg[i0 + 3] = (float)v3; }
}

__global__ void scatter_kernel(const int* __restrict__ ei, const int* __restrict__ base,
                               int* __restrict__ cursor, int* __restrict__ perm,
                               int* __restrict__ rowsS)
{
    int e = blockIdx.x * 256 + threadIdx.x;
    if (e < N_EDGES) {
        int r = ei[e];
        int p = atomicAdd(&cursor[r], 1);
        int d = base[r] + p;
        perm[d] = e;
        rowsS[d] = r;
    }
}

// ---------------- projection ----------------
__global__ __launch_bounds__(128) void proj_kernel(
    const float* __restrict__ x, const float* __restrict__ Wp, const float* __restrict__ bp,
    const float* __restrict__ Wl, const float* __restrict__ bl, float* __restrict__ h)
{
    __shared__ float xs[NB][36];
    int tid = threadIdx.x;
    int n0 = blockIdx.x * NB;
    for (int idx = tid; idx < NB * PN; idx += 128) {
        int n = idx / PN, k = idx % PN;
        xs[n][k] = x[(size_t)(n0 + n) * PN + k];
    }
    __syncthreads();
    for (int n = 0; n < NB; n++) {
        int node = n0 + n;
        bool isp = (node % NPG) < NPROT;
        float acc;
        if (isp) {
            acc = bp[tid];
            for (int k = 0; k < PN; k++) acc = fmaf(xs[n][k], Wp[k * H + tid], acc);
        } else {
            acc = bl[tid];
            for (int k = 0; k < LN; k++) acc = fmaf(xs[n][k], Wl[k * H + tid], acc);
        }
        h[(size_t)node * H + tid] = acc;
    }
}

// ---------------- batchnorm stats ----------------
__global__ __launch_bounds__(128) void bn_stats_kernel(const float* __restrict__ h, float* __restrict__ bnS)
{
    int tid = threadIdx.x;
    size_t base = (size_t)blockIdx.x * NPG * H;
    float s1 = 0.f, s2 = 0.f;
    for (int i = 0; i < NPG; i++) {
        float v = h[base + (size_t)i * H + tid];
        s1 += v; s2 += v * v;
    }
    atomicAdd(&bnS[tid], s1);
    atomicAdd(&bnS[H + tid], s2);
}

__global__ void bn_final_kernel(const float* __restrict__ bnS, const float* __restrict__ gamma,
                                const float* __restrict__ beta, float* __restrict__ bnP)
{
    int j = threadIdx.x;
    float mu = bnS[j] / (float)N_NODES;
    float var = bnS[H + j] / (float)N_NODES - mu * mu;
    float inv = rsqrtf(var + EPSV);
    float sc = gamma[j] * inv;
    bnP[j] = sc;
    bnP[H + j] = beta[j] - mu * sc;
}

// ---- hi/lo bf16 MFMA k-loop: 2 m-tiles x 2 n-tiles per wave (3-term) ----
__device__ __forceinline__ void mm_hl2(
    const short* fH, const short* fL, int stride,
    const short* __restrict__ WH, const short* __restrict__ WL,
    int nkb, int nt0, int lane, int ln, int quad, f4_t acc[2][2])
{
    #pragma unroll
    for (int mi = 0; mi < 2; mi++)
        #pragma unroll
        for (int ni = 0; ni < 2; ni++) acc[mi][ni] = (f4_t)(0.0f);
    for (int kb = 0; kb < nkb; kb++) {
        int k0 = kb * 32 + quad * 8;
        bf8_t ah0 = *(const bf8_t*)&fH[(ln) * stride + k0];
        bf8_t al0 = *(const bf8_t*)&fL[(ln) * stride + k0];
        bf8_t ah1 = *(const bf8_t*)&fH[(16 + ln) * stride + k0];
        bf8_t al1 = *(const bf8_t*)&fL[(16 + ln) * stride + k0];
        #pragma unroll
        for (int ni = 0; ni < 2; ni++) {
            int off = ((kb * 8 + nt0 + ni) * 64 + lane) * 8;
            bf8_t bh = *(const bf8_t*)&WH[off];
            bf8_t bl = *(const bf8_t*)&WL[off];
            acc[0][ni] = __builtin_amdgcn_mfma_f32_16x16x32_bf16(ah0, bh, acc[0][ni], 0, 0, 0);
            acc[0][ni] = __builtin_amdgcn_mfma_f32_16x16x32_bf16(al0, bh, acc[0][ni], 0, 0, 0);
            acc[0][ni] = __builtin_amdgcn_mfma_f32_16x16x32_bf16(ah0, bl, acc[0][ni], 0, 0, 0);
            acc[1][ni] = __builtin_amdgcn_mfma_f32_16x16x32_bf16(ah1, bh, acc[1][ni], 0, 0, 0);
            acc[1][ni] = __builtin_amdgcn_mfma_f32_16x16x32_bf16(al1, bh, acc[1][ni], 0, 0, 0);
            acc[1][ni] = __builtin_amdgcn_mfma_f32_16x16x32_bf16(ah1, bl, acc[1][ni], 0, 0, 0);
        }
    }
}

// ---- 2-term variant: bf16 activations (hi only) x exact hi/lo weights ----
__device__ __forceinline__ void mm_h2t(
    const short* fH, int stride,
    const short* __restrict__ WH, const short* __restrict__ WL,
    int nkb, int nt0, int lane, int ln, int quad, f4_t acc[2][2])
{
    #pragma unroll
    for (int mi = 0; mi < 2; mi++)
        #pragma unroll
        for (int ni = 0; ni < 2; ni++) acc[mi][ni] = (f4_t)(0.0f);
    for (int kb = 0; kb < nkb; kb++) {
        int k0 = kb * 32 + quad * 8;
        bf8_t ah0 = *(const bf8_t*)&fH[(ln) * stride + k0];
        bf8_t ah1 = *(const bf8_t*)&fH[(16 + ln) * stride + k0];
        #pragma unroll
        for (int ni = 0; ni < 2; ni++) {
            int off = ((kb * 8 + nt0 + ni) * 64 + lane) * 8;
            bf8_t bh = *(const bf8_t*)&WH[off];
            bf8_t bl = *(const bf8_t*)&WL[off];
            acc[0][ni] = __builtin_amdgcn_mfma_f32_16x16x32_bf16(ah0, bh, acc[0][ni], 0, 0, 0);
            acc[0][ni] = __builtin_amdgcn_mfma_f32_16x16x32_bf16(ah0, bl, acc[0][ni], 0, 0, 0);
            acc[1][ni] = __builtin_amdgcn_mfma_f32_16x16x32_bf16(ah1, bh, acc[1][ni], 0, 0, 0);
            acc[1][ni] = __builtin_amdgcn_mfma_f32_16x16x32_bf16(ah1, bl, acc[1][ni], 0, 0, 0);
        }
    }
}

// ---------------- layer-0 pre-projection + fused BatchNorm apply ----------------
__global__ __launch_bounds__(512, 4) void p12_kernel(
    float* __restrict__ h, const float* __restrict__ bnP,
    const short* __restrict__ Ah, const short* __restrict__ Al,
    const short* __restrict__ Bh, const short* __restrict__ Bl,
    float* __restrict__ P1, float* __restrict__ P2)
{
    __shared__ __align__(16) short fH[NBN * FS2];
    __shared__ __align__(16) short fL[NBN * FS2];
    int tid = threadIdx.x;
    int n0 = blockIdx.x * NBN;

    for (int i = tid; i < NBN * (H / 4); i += 512) {
        int nidx = i >> 5, chunk = i & 31;
        int node0 = n0 + nidx;
        int node = (node0 < N_NODES) ? node0 : (N_NODES - 1);
        int ch4 = chunk * 4;
        f4_t v = *(const f4_t*)&h[(size_t)node * H + ch4];
        f4_t sc = *(const f4_t*)&bnP[ch4];
        f4_t sh = *(const f4_t*)&bnP[H + ch4];
        bf4_t hi, lo;
        #pragma unroll
        for (int j = 0; j < 4; j++) {
            float hn = fmaf(v[j], sc[j], sh[j]);
            v[j] = hn;
            short2 s = split_hl(hn);
            hi[j] = s.x; lo[j] = s.y;
        }
        if (node0 < N_NODES) *(f4_t*)&h[(size_t)node * H + ch4] = v;   // BN applied in place
        *(bf4_t*)&fH[nidx * FS2 + ch4] = hi;
        *(bf4_t*)&fL[nidx * FS2 + ch4] = lo;
    }
    __syncthreads();

    int lane = tid & 63;
    int nt = tid >> 6;
    int ln = lane & 15, quad = lane >> 4;

    f4_t accA[4], accB[4];
    #pragma unroll
    for (int mi = 0; mi < 4; mi++) { accA[mi] = (f4_t)(0.0f); accB[mi] = (f4_t)(0.0f); }
    for (int kb = 0; kb < 4; kb++) {
        int k0 = kb * 32 + quad * 8;
        int off = ((kb * 8 + nt) * 64 + lane) * 8;
        bf8_t bhA = *(const bf8_t*)&Ah[off];
        bf8_t blA = *(const bf8_t*)&Al[off];
        bf8_t bhB = *(const bf8_t*)&Bh[off];
        bf8_t blB = *(const bf8_t*)&Bl[off];
        #pragma unroll
        for (int mi = 0; mi < 4; mi++) {
            bf8_t ah = *(const bf8_t*)&fH[(mi * 16 + ln) * FS2 + k0];
            bf8_t al = *(const bf8_t*)&fL[(mi * 16 + ln) * FS2 + k0];
            accA[mi] = __builtin_amdgcn_mfma_f32_16x16x32_bf16(ah, bhA, accA[mi], 0, 0, 0);
            accA[mi] = __builtin_amdgcn_mfma_f32_16x16x32_bf16(al, bhA, accA[mi], 0, 0, 0);
            accA[mi] = __builtin_amdgcn_mfma_f32_16x16x32_bf16(ah, blA, accA[mi], 0, 0, 0);
            accB[mi] = __builtin_amdgcn_mfma_f32_16x16x32_bf16(ah, bhB, accB[mi], 0, 0, 0);
            accB[mi] = __builtin_amdgcn_mfma_f32_16x16x32_bf16(al, bhB, accB[mi], 0, 0, 0);
            accB[mi] = __builtin_amdgcn_mfma_f32_16x16x32_bf16(ah, blB, accB[mi], 0, 0, 0);
        }
    }
    int n = nt * 16 + ln;
    #pragma unroll
    for (int mi = 0; mi < 4; mi++) {
        #pragma unroll
        for (int r = 0; r < 4; r++) {
            int node = n0 + mi * 16 + quad * 4 + r;
            if (node < N_NODES) {
                P1[(size_t)node * H + n] = accA[mi][r];
                P2[(size_t)node * H + n] = accB[mi][r];
            }
        }
    }
}

// ---------------- MFMA edge kernel (EB=32, 256 thr, 8 blocks/CU, XCD-swizzled) ----------------
__global__ __launch_bounds__(256, 8) void edge_mfma_kernel(
    const float* __restrict__ P1, const float* __restrict__ P2,
    const float* __restrict__ pos,
    const int* __restrict__ ei, const float* __restrict__ eattr,
    const int* __restrict__ perm, const int* __restrict__ rowsS,
    const float* __restrict__ W1c, const float* __restrict__ eb1,
    const short* __restrict__ W2h, const short* __restrict__ W2l,
    const short* __restrict__ W3h, const short* __restrict__ W3l,
    const float* __restrict__ eb2,
    const float* __restrict__ cb1, const float* __restrict__ cw2,
    float* __restrict__ magg, float* __restrict__ pagg)
{
    __shared__ __align__(16) short fHL[2 * EB2 * FS2];   // 17408 B
    __shared__ float relS[EB2][3];
    __shared__ float attrS[EB2][5];
    __shared__ float wpart[EB2][4];
    __shared__ int rowS[EB2];
    __shared__ int rowG[EB2];
    __shared__ int colS[EB2];

    short* fH = fHL;
    short* fL = fHL + EB2 * FS2;
    int tid = threadIdx.x;
    int chunk = gridDim.x >> 3;
    int bx = blockIdx.x;
    int bid = (bx & 7) * chunk + (bx >> 3);
    int e0 = bid * EB2;

    // --- edge meta ---
    if (tid < EB2) {
        int e = e0 + tid;
        int eidx = (e < N_EDGES) ? e : (N_EDGES - 1);
        int ec = perm[eidx];
        int r = rowsS[eidx];
        int c = ei[N_EDGES + ec];
        rowG[tid] = r;
        rowS[tid] = (e < N_EDGES) ? r : -1;
        colS[tid] = c;
        float rx = pos[r * 3 + 0] - pos[c * 3 + 0];
        float ry = pos[r * 3 + 1] - pos[c * 3 + 1];
        float rz = pos[r * 3 + 2] - pos[c * 3 + 2];
        relS[tid][0] = rx; relS[tid][1] = ry; relS[tid][2] = rz;
        attrS[tid][0] = rx * rx + ry * ry + rz * rz;
        attrS[tid][1] = eattr[(size_t)ec * 4 + 0];
        attrS[tid][2] = eattr[(size_t)ec * 4 + 1];
        attrS[tid][3] = eattr[(size_t)ec * 4 + 2];
        attrS[tid][4] = eattr[(size_t)ec * 4 + 3];
    }
    __syncthreads();

    // --- fused stage 1, pair-batched for load ILP ---
    {
        int ch4 = (tid & 31) * 4;
        f4_t bb = *(const f4_t*)&eb1[ch4];
        f4_t w0 = *(const f4_t*)&W1c[0 * H + ch4];
        f4_t w1 = *(const f4_t*)&W1c[1 * H + ch4];
        f4_t w2 = *(const f4_t*)&W1c[2 * H + ch4];
        f4_t w3 = *(const f4_t*)&W1c[3 * H + ch4];
        f4_t w4 = *(const f4_t*)&W1c[4 * H + ch4];
        #pragma unroll
        for (int b = 0; b < 2; b++) {
            int i0 = tid + b * 512;
            int i1 = i0 + 256;
            int ea = i0 >> 5;
            int eb_ = i1 >> 5;
            f4_t p1a = *(const f4_t*)&P1[(size_t)rowG[ea] * H + ch4];
            f4_t p2a = *(const f4_t*)&P2[(size_t)colS[ea] * H + ch4];
            f4_t p1b = *(const f4_t*)&P1[(size_t)rowG[eb_] * H + ch4];
            f4_t p2b = *(const f4_t*)&P2[(size_t)colS[eb_] * H + ch4];
            #pragma unroll
            for (int half = 0; half < 2; half++) {
                int e = half ? eb_ : ea;
                f4_t p1 = half ? p1b : p1a;
                f4_t p2 = half ? p2b : p2a;
                float a0 = attrS[e][0], a1 = attrS[e][1], a2 = attrS[e][2];
                float a3 = attrS[e][3], a4 = attrS[e][4];
                bf4_t hi, lo;
                #pragma unroll
                for (int j = 0; j < 4; j++) {
                    float t = p1[j] + p2[j] + bb[j];
                    t = fmaf(a0, w0[j], t);
                    t = fmaf(a1, w1[j], t);
                    t = fmaf(a2, w2[j], t);
                    t = fmaf(a3, w3[j], t);
                    t = fmaf(a4, w4[j], t);
                    float v = silu_f(t);
                    short2 s = split_hl(v);
                    hi[j] = s.x; lo[j] = s.y;
                }
                *(bf4_t*)&fH[e * FS2 + ch4] = hi;
                *(bf4_t*)&fL[e * FS2 + ch4] = lo;
            }
        }
    }
    __syncthreads();

    int lane = tid & 63;
    int wv = tid >> 6;            // 4 waves
    int ln = lane & 15, quad = lane >> 4;
    int nt0 = wv * 2;             // each wave: 2 n-tiles

    f4_t acc[2][2];
    float t2s[2][2][4];

    // ===== stage 2: t2 = silu(t1 @ W2 + b2), K=128 (3-term) =====
    mm_hl2(fH, fL, FS2, W2h, W2l, 4, nt0, lane, ln, quad, acc);
    #pragma unroll
    for (int ni = 0; ni < 2; ni++) {
        int n = (nt0 + ni) * 16 + ln;
        float bb = eb2[n];
        #pragma unroll
        for (int mi = 0; mi < 2; mi++)
            #pragma unroll
            for (int r = 0; r < 4; r++)
                t2s[mi][ni][r] = silu_f(acc[mi][ni][r] + bb);
    }
    __syncthreads();   // all stage-2 reads of t1 done
    // t2 stored hi-only (bf16): feeds stage 3 AND the magg segmented reduce
    #pragma unroll
    for (int ni = 0; ni < 2; ni++) {
        int n = (nt0 + ni) * 16 + ln;
        #pragma unroll
        for (int mi = 0; mi < 2; mi++) {
            #pragma unroll
            for (int r = 0; r < 4; r++) {
                int m = mi * 16 + quad * 4 + r;
                fH[m * FS2 + n] = f2b_fast(t2s[mi][ni][r]);
            }
        }
    }
    __syncthreads();

    // ===== stage 3: w = silu(t2 @ Wc1 + cb1) @ cw2, K=128 (2-term) =====
    mm_h2t(fH, FS2, W3h, W3l, 4, nt0, lane, ln, quad, acc);
    {
        #pragma unroll
        for (int mi = 0; mi < 2; mi++) {
            #pragma unroll
            for (int r = 0; r < 4; r++) {
                float v = 0.f;
                #pragma unroll
                for (int ni = 0; ni < 2; ni++) {
                    int n = (nt0 + ni) * 16 + ln;
                    v += silu_f(acc[mi][ni][r] + cb1[n]) * cw2[n];
                }
                v += __shfl_xor(v, 1, 64);
                v += __shfl_xor(v, 2, 64);
                v += __shfl_xor(v, 4, 64);
                v += __shfl_xor(v, 8, 64);
                if (ln == 0) wpart[mi * 16 + quad * 4 + r][wv] = v;
            }
        }
    }
    __syncthreads();   // wpart written; t2-hi still valid in fH

    // --- segmented reduction over sorted rows (t2 read back from bf16 hi-plane) ---
    {
        int ch = tid & 127, seg = tid >> 7;
        int ebeg = seg * 16, eend = ebeg + 16;
        float a2 = 0.f; int cur = -1;
        for (int e2 = ebeg; e2 < eend; e2++) {
            int r2 = rowS[e2];
            float v2 = b2f(fH[e2 * FS2 + ch]);
            if (r2 != cur) {
                if (cur >= 0) atomicAdd(&magg[(size_t)cur * H + ch], a2);
                cur = r2; a2 = v2;
            } else a2 += v2;
        }
        if (cur >= 0) atomicAdd(&magg[(size_t)cur * H + ch], a2);
    }
    if (tid < 6) {
        int ax = tid % 3, seg = tid / 3;
        int ebeg = seg * 16, eend = ebeg + 16;
        float a2 = 0.f; int cur = -1;
        for (int e2 = ebeg; e2 < eend; e2++) {
            int r2 = rowS[e2];
            float w2 = (wpart[e2][0] + wpart[e2][1] + wpart[e2][2] + wpart[e2][3]) * relS[e2][ax];
            if (r2 != cur) {
                if (cur >= 0) atomicAdd(&pagg[(size_t)cur * 3 + ax], a2);
                cur = r2; a2 = w2;
            } else a2 += w2;
        }
        if (cur >= 0) atomicAdd(&pagg[(size_t)cur * 3 + ax], a2);
    }
}

// ---------------- MFMA node kernel (NB2=32, 256 thr) + fused next-layer P1/P2 ----------------
__global__ __launch_bounds__(256, 8) void node_mfma_kernel(
    float* __restrict__ h, float* __restrict__ magg,
    float* __restrict__ pagg, const float* __restrict__ deg,
    float* __restrict__ pos,
    const short* __restrict__ N1h, const short* __restrict__ N1l,
    const short* __restrict__ N2h, const short* __restrict__ N2l,
    const float* __restrict__ nb1, const float* __restrict__ nb2,
    const short* __restrict__ Ah, const short* __restrict__ Al,
    const short* __restrict__ Bh, const short* __restrict__ Bl,
    float* __restrict__ P1, float* __restrict__ P2, int doP)
{
    __shared__ __align__(16) short fH[NB2 * CST];   // 16896 B
    __shared__ __align__(16) short fL[NB2 * CST];   // 16896 B

    int tid = threadIdx.x;
    int n0 = blockIdx.x * NB2;

    if (tid < NB2 * 3) {
        int n = tid / 3, ax = tid - n * 3;
        int node = n0 + n;
        if (node < N_NODES) {
            float d = fmaxf(deg[node], 1.0f);
            pos[node * 3 + ax] += pagg[node * 3 + ax] / d;
            if (doP) pagg[node * 3 + ax] = 0.0f;
        }
    }

    for (int i = tid; i < 2 * NB2 * (H / 4); i += 256) {
        int rrow = i >> 5, chunk = i & 31;
        int nidx = rrow & (NB2 - 1);
        int node0 = n0 + nidx;
        int node = (node0 < N_NODES) ? node0 : (N_NODES - 1);
        const float* src = (rrow < NB2) ? h : magg;
        f4_t v = *(const f4_t*)&src[(size_t)node * H + chunk * 4];
        if (rrow >= NB2 && doP && node0 < N_NODES)
            *(f4_t*)&magg[(size_t)node * H + chunk * 4] = (f4_t)(0.0f);
        bf4_t hi, lo;
        #pragma unroll
        for (int j = 0; j < 4; j++) {
            short2 s = split_hl(v[j]);
            hi[j] = s.x; lo[j] = s.y;
        }
        int dcol = ((rrow < NB2) ? 0 : H) + chunk * 4;
        *(bf4_t*)&fH[nidx * CST + dcol] = hi;
        *(bf4_t*)&fL[nidx * CST + dcol] = lo;
    }
    __syncthreads();

    int lane = tid & 63;
    int wv = tid >> 6;
    int ln = lane & 15, quad = lane >> 4;
    int nt0 = wv * 2;

    f4_t acc[2][2];
    float u1s[2][2][4];

    // stage A: u1 = silu(cat @ N1 + nb1), K=256
    mm_hl2(fH, fL, CST, N1h, N1l, 8, nt0, lane, ln, quad, acc);
    #pragma unroll
    for (int ni = 0; ni < 2; ni++) {
        int n = (nt0 + ni) * 16 + ln;
        float bb = nb1[n];
        #pragma unroll
        for (int mi = 0; mi < 2; mi++)
            #pragma unroll
            for (int r = 0; r < 4; r++)
                u1s[mi][ni][r] = silu_f(acc[mi][ni][r] + bb);
    }
    __syncthreads();
    #pragma unroll
    for (int ni = 0; ni < 2; ni++) {
        int n = (nt0 + ni) * 16 + ln;
        #pragma unroll
        for (int mi = 0; mi < 2; mi++) {
            #pragma unroll
            for (int r = 0; r < 4; r++) {
                int m = mi * 16 + quad * 4 + r;
                short2 s = split_hl(u1s[mi][ni][r]);
                fH[m * CST + n] = s.x;
                fL[m * CST + n] = s.y;
            }
        }
    }
    __syncthreads();

    // stage B: h_new = h + u1 @ N2 + nb2; write h, stage h_new hi/lo for P GEMMs
    mm_hl2(fH, fL, CST, N2h, N2l, 4, nt0, lane, ln, quad, acc);
    __syncthreads();
    #pragma unroll
    for (int ni = 0; ni < 2; ni++) {
        int n = (nt0 + ni) * 16 + ln;
        float bb = nb2[n];
        #pragma unroll
        for (int mi = 0; mi < 2; mi++) {
            #pragma unroll
            for (int r = 0; r < 4; r++) {
                int m = mi * 16 + quad * 4 + r;
                int node = n0 + m;
                int nc = (node < N_NODES) ? node : (N_NODES - 1);
                float hn = h[(size_t)nc * H + n] + acc[mi][ni][r] + bb;
                if (node < N_NODES) h[(size_t)node * H + n] = hn;
                short2 s = split_hl(hn);
                fH[m * CST + n] = s.x;
                fL[m * CST + n] = s.y;
            }
        }
    }
    if (!doP) return;
    __syncthreads();

    // fused P GEMMs for next layer: P1 = h_new@W1a, P2 = h_new@W1b (K=128)
    f4_t accA[2][2], accB[2][2];
    #pragma unroll
    for (int mi = 0; mi < 2; mi++)
        #pragma unroll
        for (int ni = 0; ni < 2; ni++) { accA[mi][ni] = (f4_t)(0.0f); accB[mi][ni] = (f4_t)(0.0f); }
    for (int kb = 0; kb < 4; kb++) {
        int k0 = kb * 32 + quad * 8;
        bf8_t ah0 = *(const bf8_t*)&fH[(ln) * CST + k0];
        bf8_t al0 = *(const bf8_t*)&fL[(ln) * CST + k0];
        bf8_t ah1 = *(const bf8_t*)&fH[(16 + ln) * CST + k0];
        bf8_t al1 = *(const bf8_t*)&fL[(16 + ln) * CST + k0];
        #pragma unroll
        for (int ni = 0; ni < 2; ni++) {
            int off = ((kb * 8 + nt0 + ni) * 64 + lane) * 8;
            bf8_t bhA = *(const bf8_t*)&Ah[off];
            bf8_t blA = *(const bf8_t*)&Al[off];
            bf8_t bhB = *(const bf8_t*)&Bh[off];
            bf8_t blB = *(const bf8_t*)&Bl[off];
            accA[0][ni] = __builtin_amdgcn_mfma_f32_16x16x32_bf16(ah0, bhA, accA[0][ni], 0, 0, 0);
            accA[0][ni] = __builtin_amdgcn_mfma_f32_16x16x32_bf16(al0, bhA, accA[0][ni], 0, 0, 0);
            accA[0][ni] = __builtin_amdgcn_mfma_f32_16x16x32_bf16(ah0, blA, accA[0][ni], 0, 0, 0);
            accA[1][ni] = __builtin_amdgcn_mfma_f32_16x16x32_bf16(ah1, bhA, accA[1][ni], 0, 0, 0);
            accA[1][ni] = __builtin_amdgcn_mfma_f32_16x16x32_bf16(al1, bhA, accA[1][ni], 0, 0, 0);
            accA[1][ni] = __builtin_amdgcn_mfma_f32_16x16x32_bf16(ah1, blA, accA[1][ni], 0, 0, 0);
            accB[0][ni] = __builtin_amdgcn_mfma_f32_16x16x32_bf16(ah0, bhB, accB[0][ni], 0, 0, 0);
            accB[0][ni] = __builtin_amdgcn_mfma_f32_16x16x32_bf16(al0, bhB, accB[0][ni], 0, 0, 0);
            accB[0][ni] = __builtin_amdgcn_mfma_f32_16x16x32_bf16(ah0, blB, accB[0][ni], 0, 0, 0);
            accB[1][ni] = __builtin_amdgcn_mfma_f32_16x16x32_bf16(ah1, bhB, accB[1][ni], 0, 0, 0);
            accB[1][ni] = __builtin_amdgcn_mfma_f32_16x16x32_bf16(al1, bhB, accB[1][ni], 0, 0, 0);
            accB[1][ni] = __builtin_amdgcn_mfma_f32_16x16x32_bf16(ah1, blB, accB[1][ni], 0, 0, 0);
        }
    }
    #pragma unroll
    for (int ni = 0; ni < 2; ni++) {
        int n = (nt0 + ni) * 16 + ln;
        #pragma unroll
        for (int mi = 0; mi < 2; mi++) {
            #pragma unroll
            for (int r = 0; r < 4; r++) {
                int node = n0 + mi * 16 + quad * 4 + r;
                if (node < N_NODES) {
                    P1[(size_t)node * H + n] = accA[mi][ni][r];
                    P2[(size_t)node * H + n] = accB[mi][ni][r];
                }
            }
        }
    }
}

// ---------------- pooling + head ----------------
__global__ __launch_bounds__(128) void head_kernel(
    const float* __restrict__ h,
    const float* __restrict__ h1w, const float* __restrict__ h1b,
    const float* __restrict__ h2w, const float* __restrict__ h2b,
    const float* __restrict__ h3w, const float* __restrict__ h3b,
    float* __restrict__ out)
{
    __shared__ float gfeat[256];
    __shared__ float z1[128];
    __shared__ float z2[64];
    int tid = threadIdx.x;
    int g = blockIdx.x;
    size_t base = (size_t)g * NPG * H;
    float s = 0.f;
    for (int i = 0; i < NPG; i++) s += h[base + (size_t)i * H + tid];
    gfeat[tid] = s;
    gfeat[H + tid] = s / (float)NPG;
    __syncthreads();
    float a = h1b[tid];
    for (int k = 0; k < 256; k++) a = fmaf(gfeat[k], h1w[k * H + tid], a);
    z1[tid] = fmaxf(a, 0.0f);
    __syncthreads();
    if (tid < 64) {
        float a2 = h2b[tid];
        for (int k = 0; k < 128; k++) a2 = fmaf(z1[k], h2w[k * 64 + tid], a2);
        z2[tid] = fmaxf(a2, 0.0f);
    }
    __syncthreads();
    if (tid < 64) {
        float v = z2[tid] * h3w[tid];
        #pragma unroll
        for (int off = 32; off > 0; off >>= 1) v += __shfl_xor(v, off, 64);
        if (tid == 0) out[g] = v + h3b[0];
    }
}

extern "C" void kernel_launch(void* const* d_in, const int* in_sizes, int n_in,
                              void* d_out, int out_size, void* d_ws, size_t ws_size,
                              hipStream_t stream) {
    const float* x      = (const float*)d_in[0];
    const float* pos_in = (const float*)d_in[1];
    const int*   ei     = (const int*)d_in[2];
    const float* eattr  = (const float*)d_in[3];
    const float* Wp    = (const float*)d_in[6];
    const float* bp    = (const float*)d_in[7];
    const float* Wl    = (const float*)d_in[8];
    const float* bl    = (const float*)d_in[9];
    const float* gamma = (const float*)d_in[10];
    const float* beta  = (const float*)d_in[11];
    const float* ew1   = (const float*)d_in[12];
    const float* eb1   = (const float*)d_in[13];
    const float* ew2   = (const float*)d_in[14];
    const float* eb2   = (const float*)d_in[15];
    const float* cw1   = (const float*)d_in[16];
    const float* cb1   = (const float*)d_in[17];
    const float* cw2   = (const float*)d_in[18];
    const float* nw1   = (const float*)d_in[19];
    const float* nb1   = (const float*)d_in[20];
    const float* nw2   = (const float*)d_in[21];
    const float* nb2   = (const float*)d_in[22];
    const float* h1w   = (const float*)d_in[23];
    const float* h1b   = (const float*)d_in[24];
    const float* h2w   = (const float*)d_in[25];
    const float* h2b   = (const float*)d_in[26];
    const float* h3w   = (const float*)d_in[27];
    const float* h3b   = (const float*)d_in[28];
    float* out = (float*)d_out;

    float* ws   = (float*)d_ws;
    float* hbuf = ws;                                  // N*H f32
    float* magg = hbuf + (size_t)N_NODES * H;          // N*H f32
    float* P1   = magg + (size_t)N_NODES * H;          // N*H f32
    float* P2   = P1 + (size_t)N_NODES * H;            // N*H f32
    float* posb = P2 + (size_t)N_NODES * H;            // N*3
    float* pagg = posb + (size_t)N_NODES * 3;          // N*3
    float* deg  = pagg + (size_t)N_NODES * 3;          // N
    float* bnS  = deg + N_NODES;                       // 256
    float* bnP  = bnS + 256;                           // 256
    int* cnt    = (int*)(bnP + 256);                   // N
    int* basep  = cnt + N_NODES;                       // N
    int* cursor = basep + N_NODES;                     // N
    int* perm   = cursor + N_NODES;                    // E
    int* rowsS  = perm + N_EDGES;                      // E
    int* bsum   = rowsS + N_EDGES;                     // 64
    int* boff   = bsum + 64;                           // 64
    int szK4 = 4 * 4 * 4096;
    int szK8 = 4 * 8 * 4096;
    short* W1aH = (short*)(boff + 64);
    short* W1aL = W1aH + szK4;
    short* W1bH = W1aL + szK4;
    short* W1bL = W1bH + szK4;
    short* W2h  = W1bL + szK4;
    short* W2l  = W2h + szK4;
    short* W3h  = W2l + szK4;
    short* W3l  = W3h + szK4;
    short* N1h  = W3l + szK4;
    short* N1l  = N1h + szK8;
    short* N2h  = N1l + szK8;
    short* N2l  = N2h + szK4;

    (void)hipMemcpyAsync(posb, pos_in, (size_t)N_NODES * 3 * sizeof(float),
                         hipMemcpyDeviceToDevice, stream);
    (void)hipMemsetAsync(cnt, 0, N_NODES * sizeof(int), stream);
    (void)hipMemsetAsync(cursor, 0, N_NODES * sizeof(int), stream);
    (void)hipMemsetAsync(bnS, 0, 256 * sizeof(float), stream);
    (void)hipMemsetAsync(magg, 0, (size_t)N_NODES * H * sizeof(float), stream);
    (void)hipMemsetAsync(pagg, 0, (size_t)N_NODES * 3 * sizeof(float), stream);

    hist_kernel<<<(N_EDGES + 255) / 256, 256, 0, stream>>>(ei, cnt);
    bsum_kernel<<<NCHUNK, 256, 0, stream>>>(cnt, bsum);
    scanb_kernel<<<1, 64, 0, stream>>>(bsum, boff);
    scanc_kernel<<<NCHUNK, 256, 0, stream>>>(cnt, boff, basep, deg);
    scatter_kernel<<<(N_EDGES + 255) / 256, 256, 0, stream>>>(ei, basep, cursor, perm, rowsS);

    wprep_all_kernel<<<458752 / 256, 256, 0, stream>>>(
        ew1, ew2, cw1, nw1, nw2,
        W1aH, W1aL, W1bH, W1bL, W2h, W2l, W3h, W3l, N1h, N1l, N2h, N2l);

    proj_kernel<<<N_NODES / NB, 128, 0, stream>>>(x, Wp, bp, Wl, bl, hbuf);
    bn_stats_kernel<<<N_NODES / NPG, 128, 0, stream>>>(hbuf, bnS);
    bn_final_kernel<<<1, 128, 0, stream>>>(bnS, gamma, beta, bnP);

    int eblocks = (N_EDGES + EB2 - 1) / EB2;
    int echunk = (eblocks + 7) / 8;
    int eblocks_pad = echunk * 8;
    int nblocks = (N_NODES + NBN - 1) / NBN;     // p12 (64-node)
    int nblocks2 = (N_NODES + NB2 - 1) / NB2;    // node kernel (32-node)

    // layer-0 P1/P2 with fused BatchNorm apply (h updated in place)
    p12_kernel<<<nblocks, 512, 0, stream>>>(hbuf, bnP, W1aH, W1aL, W1bH, W1bL, P1, P2);

    for (int l = 0; l < 4; l++) {
        edge_mfma_kernel<<<eblocks_pad, 256, 0, stream>>>(
            P1, P2, posb, ei, eattr, perm, rowsS,
            ew1 + (size_t)l * DIN * H + (size_t)2 * H * H,   // W1c rows 256..260
            eb1 + (size_t)l * H,
            W2h + (size_t)l * 4 * 4096, W2l + (size_t)l * 4 * 4096,
            W3h + (size_t)l * 4 * 4096, W3l + (size_t)l * 4 * 4096,
            eb2 + (size_t)l * H,
            cb1 + (size_t)l * H, cw2 + (size_t)l * H,
            magg, pagg);
        int lp = l + 1;
        node_mfma_kernel<<<nblocks2, 256, 0, stream>>>(
            hbuf, magg, pagg, deg, posb,
            N1h + (size_t)l * 8 * 4096, N1l + (size_t)l * 8 * 4096,
            N2h + (size_t)l * 4 * 4096, N2l + (size_t)l * 4 * 4096,
            nb1 + (size_t)l * H, nb2 + (size_t)l * H,
            W1aH + (size_t)(lp & 3) * 4 * 4096, W1aL + (size_t)(lp & 3) * 4 * 4096,
            W1bH + (size_t)(lp & 3) * 4 * 4096, W1bL + (size_t)(lp & 3) * 4 * 4096,
            P1, P2, (l < 3) ? 1 : 0);
    }

    head_kernel<<<G_GRAPHS, 128, 0, stream>>>(hbuf, h1w, h1b, h2w, h2b, h3w, h3b, out);
}